// Round 8
// baseline (445.913 us; speedup 1.0000x reference)
//
#include <hip/hip_runtime.h>
#include <hip/hip_bf16.h>

// Sizes fixed by the problem
#define B  2048
#define D  4096
#define D3 12288   // 3*D
#define L  3

struct Ptrs8 { const float* p[8]; };

typedef float          f32x4 __attribute__((ext_vector_type(4)));
typedef unsigned int   u32x2 __attribute__((ext_vector_type(2)));
typedef unsigned short u16x4 __attribute__((ext_vector_type(4)));

__device__ __forceinline__ f32x4 ldnt4(const float* p) {
    return __builtin_nontemporal_load(reinterpret_cast<const f32x4*>(p));
}
__device__ __forceinline__ f32x4 ld4(const float* p) {
    return *reinterpret_cast<const f32x4*>(p);
}
__device__ __forceinline__ unsigned short f2bf(float f) {
    union { float f; unsigned int u; } v; v.f = f;
    unsigned int r = v.u + 0x7FFFu + ((v.u >> 16) & 1u);  // round-nearest-even
    return (unsigned short)(r >> 16);
}
__device__ __forceinline__ float bf_lo(unsigned int u) {
    union { unsigned int u; float f; } v; v.u = u << 16; return v.f;
}
__device__ __forceinline__ float bf_hi(unsigned int u) {
    union { unsigned int u; float f; } v; v.u = u & 0xFFFF0000u; return v.f;
}

// ---------------------------------------------------------------------------
// K1: column means of the 8 [B, D] inputs — r3 champion config.
// grid (4, 16, 8), 128 rows/block, NT loads.
// ---------------------------------------------------------------------------
__global__ void k_mean_partial(Ptrs8 in, float* __restrict__ partials) {
    const int cc = blockIdx.x, rc = blockIdx.y, m = blockIdx.z;
    const float* __restrict__ src = in.p[m];
    const int col0 = cc * 1024 + threadIdx.x * 4;
    const int row0 = rc * 128;
    f32x4 acc = {0.f, 0.f, 0.f, 0.f};
    for (int r = 0; r < 128; ++r) {
        acc += ldnt4(src + (size_t)(row0 + r) * D + col0);
    }
    *reinterpret_cast<f32x4*>(partials + ((size_t)(m * 16 + rc)) * D + col0) = acc;
}

__global__ void k_mean_finalize(const float* __restrict__ partials,
                                float* __restrict__ means,
                                float* __restrict__ h,
                                float* __restrict__ svec) {
    const int d = blockIdx.x * 256 + threadIdx.x;
    float mv[8];
    #pragma unroll
    for (int m = 0; m < 8; ++m) {
        float s = 0.f;
        #pragma unroll
        for (int rc = 0; rc < 16; ++rc) s += partials[(size_t)(m * 16 + rc) * D + d];
        mv[m] = s * (1.0f / (float)B);
        means[m * D + d] = mv[m];
    }
    float ssum = 0.f;
    #pragma unroll
    for (int j = 0; j < 4; ++j) {          // shared rows = pre means (inputs 4..7)
        h[j * D + d] = mv[4 + j];
        ssum += mv[4 + j];
    }
    #pragma unroll
    for (int s = 0; s < 4; ++s)            // stream rows = now means (inputs 0..3)
        h[(4 + s) * D + d] = mv[s];
    svec[d] = ssum;
}

// ---------------------------------------------------------------------------
// K3: aggmsg[d'] = sum_d svec[d] * W[d][d'] — r3 champion config.
// grid (4, 64), 64 rows/block, NT on W.
// ---------------------------------------------------------------------------
__global__ void k_aggmsg_partial(const float* __restrict__ Wl,
                                 const float* __restrict__ svec,
                                 float* __restrict__ partials) {
    const int col0 = blockIdx.x * 1024 + threadIdx.x * 4;
    const int row0 = blockIdx.y * 64;
    f32x4 acc = {0.f, 0.f, 0.f, 0.f};
    for (int r = 0; r < 64; ++r) {
        const float sv = svec[row0 + r];
        acc += sv * ldnt4(Wl + (size_t)(row0 + r) * D + col0);
    }
    *reinterpret_cast<f32x4*>(partials + (size_t)blockIdx.y * D + col0) = acc;
}

__global__ void k_aggmsg_reduce(const float* __restrict__ partials,
                                float* __restrict__ aggmsg) {
    const int d = blockIdx.x * 256 + threadIdx.x;
    float s = 0.f;
    #pragma unroll
    for (int r = 0; r < 64; ++r) s += partials[(size_t)r * D + d];
    aggmsg[d] = s;
}

// ---------------------------------------------------------------------------
// K4 (layer 0): r2 CHAMPION structure, verbatim (130 µs measured).
// Waves 0..3071: gh (4 w_hh rows/wave, all 8 h). Waves 3072..6143: gi0.
// Plain loads, w-then-h order, fused bf16 conversion store.
// ---------------------------------------------------------------------------
__global__ void k_gates_f32(const float* __restrict__ w_ih,
                            const float* __restrict__ w_hh,
                            const float* __restrict__ h,
                            const float* __restrict__ aggmsg,
                            const float* __restrict__ b_ih,
                            const float* __restrict__ b_hh,
                            float* __restrict__ gi0,
                            float* __restrict__ gh,
                            unsigned short* __restrict__ wih_bf,
                            unsigned short* __restrict__ whh_bf) {
    const int gwid = (blockIdx.x * blockDim.x + threadIdx.x) >> 6;
    const int lane = threadIdx.x & 63;
    if (gwid < 3072) {
        const int k0 = gwid * 4;
        float acc[4][8] = {};
        for (int i = 0; i < 16; ++i) {
            const int idx = i * 256 + lane * 4;
            f32x4 w[4];
            #pragma unroll
            for (int r = 0; r < 4; ++r)
                w[r] = ld4(w_hh + (size_t)(k0 + r) * D + idx);
            #pragma unroll
            for (int r = 0; r < 4; ++r) {
                u16x4 wb;
                wb.x = f2bf(w[r].x); wb.y = f2bf(w[r].y);
                wb.z = f2bf(w[r].z); wb.w = f2bf(w[r].w);
                *reinterpret_cast<u16x4*>(whh_bf + (size_t)(k0 + r) * D + idx) = wb;
            }
            f32x4 hv[8];
            #pragma unroll
            for (int j = 0; j < 8; ++j) hv[j] = ld4(h + j * D + idx);
            #pragma unroll
            for (int r = 0; r < 4; ++r)
                #pragma unroll
                for (int j = 0; j < 8; ++j)
                    acc[r][j] += w[r].x * hv[j].x + w[r].y * hv[j].y
                               + w[r].z * hv[j].z + w[r].w * hv[j].w;
        }
        #pragma unroll
        for (int r = 0; r < 4; ++r)
            #pragma unroll
            for (int j = 0; j < 8; ++j) {
                float v = acc[r][j];
                #pragma unroll
                for (int off = 32; off; off >>= 1) v += __shfl_xor(v, off);
                if (lane == 0) gh[(size_t)j * D3 + k0 + r] = v + b_hh[k0 + r];
            }
    } else {
        const int k0 = (gwid - 3072) * 4;
        float acc[4] = {0.f, 0.f, 0.f, 0.f};
        for (int i = 0; i < 16; ++i) {
            const int idx = i * 256 + lane * 4;
            const f32x4 a = ld4(aggmsg + idx);
            #pragma unroll
            for (int r = 0; r < 4; ++r) {
                const f32x4 w = ld4(w_ih + (size_t)(k0 + r) * D + idx);
                u16x4 wb;
                wb.x = f2bf(w.x); wb.y = f2bf(w.y);
                wb.z = f2bf(w.z); wb.w = f2bf(w.w);
                *reinterpret_cast<u16x4*>(wih_bf + (size_t)(k0 + r) * D + idx) = wb;
                acc[r] += w.x * a.x + w.y * a.y + w.z * a.z + w.w * a.w;
            }
        }
        #pragma unroll
        for (int r = 0; r < 4; ++r) {
            float v = acc[r];
            #pragma unroll
            for (int off = 32; off; off >>= 1) v += __shfl_xor(v, off);
            if (lane == 0) gi0[k0 + r] = v + b_ih[k0 + r];
        }
    }
}

// ---------------------------------------------------------------------------
// K4b (layers 1-2): gates from bf16 copies. Spill-proof live sets:
// hh waves: 2 rows (w=4 + hv[8]=32 + acc[2][8]=16 ~= 52 live < 64).
// ih waves: 8 rows (w=16 + av=4 + acc[8]=8 ~= 35 live).
// Champion-style simple loop: weights first, then h, consume.
// Blocks [0,1536): hh. Blocks [1536,1920): ih.
// ---------------------------------------------------------------------------
__global__ void k_gates_bf(const unsigned short* __restrict__ wih_bf,
                           const unsigned short* __restrict__ whh_bf,
                           const float* __restrict__ h,
                           const float* __restrict__ aggmsg,
                           const float* __restrict__ b_ih,
                           const float* __restrict__ b_hh,
                           float* __restrict__ gi0,
                           float* __restrict__ gh) {
    const int wid = threadIdx.x >> 6, lane = threadIdx.x & 63;
    const int col = lane * 4;
    if (blockIdx.x < 1536) {
        const int k0 = (blockIdx.x * 4 + wid) * 2;   // 2 rows/wave
        const unsigned short* __restrict__ wr0 = whh_bf + (size_t)k0 * D;
        const unsigned short* __restrict__ wr1 = wr0 + D;
        float acc0[8] = {}, acc1[8] = {};
        for (int i = 0; i < 16; ++i) {
            const int idx = i * 256 + col;
            const u32x2 wa0 = *reinterpret_cast<const u32x2*>(wr0 + idx);
            const u32x2 wa1 = *reinterpret_cast<const u32x2*>(wr1 + idx);
            f32x4 hv[8];
            #pragma unroll
            for (int j = 0; j < 8; ++j) hv[j] = ld4(h + j * D + idx);
            const float a0 = bf_lo(wa0.x), a1 = bf_hi(wa0.x);
            const float a2 = bf_lo(wa0.y), a3 = bf_hi(wa0.y);
            const float c0 = bf_lo(wa1.x), c1 = bf_hi(wa1.x);
            const float c2 = bf_lo(wa1.y), c3 = bf_hi(wa1.y);
            #pragma unroll
            for (int j = 0; j < 8; ++j) {
                acc0[j] += a0 * hv[j].x + a1 * hv[j].y + a2 * hv[j].z + a3 * hv[j].w;
                acc1[j] += c0 * hv[j].x + c1 * hv[j].y + c2 * hv[j].z + c3 * hv[j].w;
            }
        }
        #pragma unroll
        for (int j = 0; j < 8; ++j) {
            float v0 = acc0[j], v1 = acc1[j];
            #pragma unroll
            for (int off = 32; off; off >>= 1) {
                v0 += __shfl_xor(v0, off);
                v1 += __shfl_xor(v1, off);
            }
            if (lane == 0) {
                gh[(size_t)j * D3 + k0 + 0] = v0 + b_hh[k0 + 0];
                gh[(size_t)j * D3 + k0 + 1] = v1 + b_hh[k0 + 1];
            }
        }
    } else {
        const int k0 = ((blockIdx.x - 1536) * 4 + wid) * 8;  // 8 rows/wave
        const unsigned short* __restrict__ wr = wih_bf + (size_t)k0 * D;
        float acc[8] = {};
        for (int i = 0; i < 16; ++i) {
            const int idx = i * 256 + col;
            u32x2 w[8];
            #pragma unroll
            for (int r = 0; r < 8; ++r)
                w[r] = *reinterpret_cast<const u32x2*>(wr + (size_t)r * D + idx);
            const f32x4 av = ld4(aggmsg + idx);
            #pragma unroll
            for (int r = 0; r < 8; ++r)
                acc[r] += bf_lo(w[r].x) * av.x + bf_hi(w[r].x) * av.y
                        + bf_lo(w[r].y) * av.z + bf_hi(w[r].y) * av.w;
        }
        #pragma unroll
        for (int r = 0; r < 8; ++r) {
            float v = acc[r];
            #pragma unroll
            for (int off = 32; off; off >>= 1) v += __shfl_xor(v, off);
            if (lane == 0) gi0[k0 + r] = v + b_ih[k0 + r];
        }
    }
}

// ---------------------------------------------------------------------------
// K6: GRU pointwise update; rows 0-3 (shared) use gi = b_ih (agg = 0).
// ---------------------------------------------------------------------------
__device__ __forceinline__ float sigmoidf_(float x) {
    return 1.0f / (1.0f + __expf(-x));
}

__global__ void k_gru(const float* __restrict__ gi0,
                      const float* __restrict__ gh,
                      const float* __restrict__ b_ih,
                      float* __restrict__ h,
                      float* __restrict__ svec) {
    const int d = blockIdx.x * 256 + threadIdx.x;
    const float bir = b_ih[d], biz = b_ih[D + d], bin = b_ih[2 * D + d];
    const float gir = gi0[d],  giz = gi0[D + d],  gin = gi0[2 * D + d];
    float ssum = 0.f;
    #pragma unroll
    for (int j = 0; j < 8; ++j) {
        const float ir = (j < 4) ? bir : gir;
        const float iz = (j < 4) ? biz : giz;
        const float in = (j < 4) ? bin : gin;
        const float hr = gh[(size_t)j * D3 + d];
        const float hz = gh[(size_t)j * D3 + D + d];
        const float hn = gh[(size_t)j * D3 + 2 * D + d];
        const float hv = h[j * D + d];
        const float r = sigmoidf_(ir + hr);
        const float z = sigmoidf_(iz + hz);
        const float n = tanhf(in + r * hn);
        const float hnew = (1.f - z) * n + z * hv;
        h[j * D + d] = hnew;
        if (j < 4) ssum += hnew;
    }
    svec[d] = ssum;
}

// ---------------------------------------------------------------------------
// K7: loss = 10 * sum_s mean_d (h0_s - pre_mean_s)^2.
// ---------------------------------------------------------------------------
__global__ void k_loss(const float* __restrict__ h,
                       const float* __restrict__ means,
                       float* __restrict__ out) {
    __shared__ float red[4];
    float acc = 0.f;
    for (int idx = threadIdx.x; idx < 4 * D; idx += 256) {
        const int s = idx >> 12;
        const int d = idx & (D - 1);
        const float diff = h[(4 + s) * D + d] - means[(4 + s) * D + d];
        acc += diff * diff;
    }
    #pragma unroll
    for (int off = 32; off; off >>= 1) acc += __shfl_xor(acc, off);
    const int wave = threadIdx.x >> 6, lane = threadIdx.x & 63;
    if (lane == 0) red[wave] = acc;
    __syncthreads();
    if (threadIdx.x == 0)
        out[0] = (red[0] + red[1] + red[2] + red[3]) * (10.0f / (float)D);
}

// ---------------------------------------------------------------------------
extern "C" void kernel_launch(void* const* d_in, const int* in_sizes, int n_in,
                              void* d_out, int out_size, void* d_ws, size_t ws_size,
                              hipStream_t stream) {
    const float* W    = (const float*)d_in[8];
    const float* w_ih = (const float*)d_in[9];
    const float* w_hh = (const float*)d_in[10];
    const float* b_ih = (const float*)d_in[11];
    const float* b_hh = (const float*)d_in[12];

    float* ws     = (float*)d_ws;
    float* mpart  = ws;                    // 8*16*D
    float* means  = mpart  + 8 * 16 * D;   // 8*D
    float* h      = means  + 8 * D;        // 8*D
    float* svec   = h      + 8 * D;        // D
    float* apart  = svec   + D;            // 64*D
    float* aggmsg = apart  + 64 * D;       // D
    float* gi0    = aggmsg + D;            // D3
    float* gh     = gi0    + D3;           // 8*D3
    float* wbase  = gh     + 8 * D3;
    unsigned short* wih_bf = (unsigned short*)wbase;   // D3*D bf16 = 96 MB
    unsigned short* whh_bf = wih_bf + (size_t)D3 * D;  // D3*D bf16 = 96 MB

    Ptrs8 in8;
    for (int i = 0; i < 8; ++i) in8.p[i] = (const float*)d_in[i];

    k_mean_partial<<<dim3(4, 16, 8), 256, 0, stream>>>(in8, mpart);
    k_mean_finalize<<<16, 256, 0, stream>>>(mpart, means, h, svec);

    for (int l = 0; l < L; ++l) {
        const float* Wl = W + (size_t)l * D * D;
        k_aggmsg_partial<<<dim3(4, 64), 256, 0, stream>>>(Wl, svec, apart);
        k_aggmsg_reduce<<<16, 256, 0, stream>>>(apart, aggmsg);
        if (l == 0)
            k_gates_f32<<<1536, 256, 0, stream>>>(w_ih, w_hh, h, aggmsg,
                                                  b_ih, b_hh, gi0, gh,
                                                  wih_bf, whh_bf);
        else
            k_gates_bf<<<1920, 256, 0, stream>>>(wih_bf, whh_bf, h, aggmsg,
                                                 b_ih, b_hh, gi0, gh);
        k_gru<<<16, 256, 0, stream>>>(gi0, gh, b_ih, h, svec);
    }

    k_loss<<<1, 256, 0, stream>>>(h, means, (float*)d_out);
}